// Round 2
// baseline (1097.646 us; speedup 1.0000x reference)
//
#include <hip/hip_runtime.h>

#define HH 64
#define WW 64
#define TT 100
#define CO 8
#define KS 6
#define LP 2
#define HALO 21    // 16 + KS - 1
#define NSITE 441  // 21*21
#define NG 5       // float4-groups per chunk (TC = 20 timesteps)
#define SLOT_PAD 2304   // 9*256 >= NSITE*NG = 2205 (over-staged, clamped src)

__device__ __forceinline__ float stepu(float u, float s, float th, float wx) {
    // u = (u - s*th) + wx  -- exact reference association, no contraction
    return __fadd_rn(__fsub_rn(u, __fmul_rn(s, th)), wx);
}

// async global->LDS DMA, 16B per lane; LDS dest is wave-uniform base + lane*16,
// which matches dst[tid + k*256] for consecutive-tid lanes.
#define GLDS16(gp, lp) \
    __builtin_amdgcn_global_load_lds((const __attribute__((address_space(1))) void*)(gp), \
                                     (__attribute__((address_space(3))) void*)(lp), 16, 0, 0)

__device__ __forceinline__ void stage_chunk(const float* __restrict__ xb,
                                            float4* __restrict__ dst,
                                            const int* __restrict__ offs,
                                            int tid, int t0)
{
#pragma unroll
    for (int k = 0; k < 9; ++k) {
        GLDS16(xb + offs[k] + t0, dst + tid + k * 256);
    }
}

#define FMA4(ACC, WD) \
    ACC.x = __fmaf_rn((WD), xv.x, ACC.x); \
    ACC.y = __fmaf_rn((WD), xv.y, ACC.y); \
    ACC.z = __fmaf_rn((WD), xv.z, ACC.z); \
    ACC.w = __fmaf_rn((WD), xv.w, ACC.w);

#define SCAN4(J) { \
    float u = ut[J], s = sprev[J]; unsigned m = 0u; \
    u = stepu(u, s, th, wx[J].x); s = (u > 0.f) ? 1.f : 0.f; m |= (u > 0.f) ? 1u : 0u; \
    u = stepu(u, s, th, wx[J].y); s = (u > 0.f) ? 1.f : 0.f; m |= (u > 0.f) ? 2u : 0u; \
    u = stepu(u, s, th, wx[J].z); s = (u > 0.f) ? 1.f : 0.f; m |= (u > 0.f) ? 4u : 0u; \
    u = stepu(u, s, th, wx[J].w); s = (u > 0.f) ? 1.f : 0.f; m |= (u > 0.f) ? 8u : 0u; \
    ut[J] = u; sprev[J] = s; cb[J] |= m << sh; }

template<int T0>
__device__ __forceinline__ void compute_chunk(
    const float4* __restrict__ xsb, const float4 (*__restrict__ wds4)[2],
    int base, float th, const float* __restrict__ vr, const float* __restrict__ vc,
    float* ut, float* sprev, unsigned* bw)
{
    unsigned cb[CO];
#pragma unroll
    for (int j = 0; j < CO; ++j) cb[j] = 0u;

#pragma unroll 1               // keep per-tg weight broadcasts inside (no 288-reg hoist)
    for (int tg = 0; tg < NG; ++tg) {
        float4 wx[CO];
#pragma unroll
        for (int j = 0; j < CO; ++j) wx[j] = make_float4(0.f, 0.f, 0.f, 0.f);
#pragma unroll
        for (int kh = 0; kh < KS; ++kh) {
#pragma unroll
            for (int kw = 0; kw < KS; ++kw) {
                const int tap = kh * KS + kw;
                float4 xv = xsb[base + (kh * HALO + kw) * NG + tg];
                // zero-padding emulation: f = 1.0 inside image, 0.0 in halo pad.
                // valid: x*1.0 bit-exact; invalid: fma(wd, +-0, wx) == wx.
                const float f = __fmul_rn(vr[kh], vc[kw]);
                xv.x = __fmul_rn(xv.x, f);
                xv.y = __fmul_rn(xv.y, f);
                xv.z = __fmul_rn(xv.z, f);
                xv.w = __fmul_rn(xv.w, f);
                const float4 wa = wds4[tap][0];   // couts 0..3 (broadcast b128)
                const float4 wb = wds4[tap][1];   // couts 4..7
                FMA4(wx[0], wa.x); FMA4(wx[1], wa.y);
                FMA4(wx[2], wa.z); FMA4(wx[3], wa.w);
                FMA4(wx[4], wb.x); FMA4(wx[5], wb.y);
                FMA4(wx[6], wb.z); FMA4(wx[7], wb.w);
            }
        }
        const int sh = tg * 4;
        SCAN4(0); SCAN4(1); SCAN4(2); SCAN4(3);
        SCAN4(4); SCAN4(5); SCAN4(6); SCAN4(7);
    }

    constexpr int W0 = T0 / 32;
    constexpr int S  = T0 % 32;
#pragma unroll
    for (int j = 0; j < CO; ++j) {
        bw[j * 4 + W0] |= cb[j] << S;
        if constexpr (S + 20 > 32)
            bw[j * 4 + W0 + 1] |= cb[j] >> (32 - S);
    }
}

__global__ __launch_bounds__(256, 2)
void sconv2d_spike_kernel(const float* __restrict__ x,
                          const float* __restrict__ wgt,
                          const float* __restrict__ thresh,
                          float* __restrict__ out)
{
    __shared__ float4 xs[2][SLOT_PAD];     // 73.7 KB (double-buffered chunks)
    __shared__ float4 wds4[KS * KS][2];    // 1.2 KB: [tap][co-half] as float4

    const int tid = threadIdx.x;
    for (int i = tid; i < KS * KS * CO; i += 256) {
        const int co  = i / (KS * KS);
        const int tap = i - co * (KS * KS);
        ((float*)wds4)[tap * 8 + co] = wgt[i];
    }
    const float th = thresh[0];

    // grid = 32 images x 16 tiles; all 8 couts per block (512 blocks = 2/CU exact)
    const int blk = blockIdx.x;
    const int b   = blk >> 4;
    const int tb  = blk & 15;
    const int h0  = (tb >> 2) << 4;
    const int w0  = (tb & 3) << 4;
    const int r   = tid >> 4;
    const int c   = tid & 15;

    const float* xb = x + (size_t)b * (HH * WW * TT);

    // per-thread staging source offsets, coordinates CLAMPED into the image
    // (never OOB; padding correctness restored by vr/vc validity factors)
    int offs[9];
#pragma unroll
    for (int k = 0; k < 9; ++k) {
        const int i = tid + k * 256;
        int s  = i / NG;
        int tg = i - s * NG;
        if (s >= NSITE) { s = NSITE - 1; tg = 0; }   // clamp over-staged slots
        const int hr = s / HALO;
        const int hc = s - hr * HALO;
        int hh = h0 - LP + hr; hh = hh < 0 ? 0 : (hh > HH - 1 ? HH - 1 : hh);
        int ww = w0 - LP + hc; ww = ww < 0 ? 0 : (ww > WW - 1 ? WW - 1 : ww);
        offs[k] = (hh * WW + ww) * TT + tg * 4;
    }

    // per-thread zero-padding validity factors (site r+kh, c+kw)
    float vr[KS], vc[KS];
#pragma unroll
    for (int kk = 0; kk < KS; ++kk) {
        vr[kk] = ((unsigned)(h0 - LP + r + kk) < (unsigned)HH) ? 1.f : 0.f;
        vc[kk] = ((unsigned)(w0 - LP + c + kk) < (unsigned)WW) ? 1.f : 0.f;
    }

    float ut[CO], sprev[CO];
    unsigned bw[CO * 4];
#pragma unroll
    for (int j = 0; j < CO; ++j) { ut[j] = 0.f; sprev[j] = 0.f; }
#pragma unroll
    for (int i = 0; i < CO * 4; ++i) bw[i] = 0u;

    const int base = (r * HALO + c) * NG;

    // 2-phase pipeline: issue stage(t+1) before compute(t); 1 barrier per chunk
    stage_chunk(xb, xs[0], offs, tid, 0);
    __syncthreads();

    stage_chunk(xb, xs[1], offs, tid, 20);
    compute_chunk< 0>(xs[0], wds4, base, th, vr, vc, ut, sprev, bw);
    __syncthreads();

    stage_chunk(xb, xs[0], offs, tid, 40);
    compute_chunk<20>(xs[1], wds4, base, th, vr, vc, ut, sprev, bw);
    __syncthreads();

    stage_chunk(xb, xs[1], offs, tid, 60);
    compute_chunk<40>(xs[0], wds4, base, th, vr, vc, ut, sprev, bw);
    __syncthreads();

    stage_chunk(xb, xs[0], offs, tid, 80);
    compute_chunk<60>(xs[1], wds4, base, th, vr, vc, ut, sprev, bw);
    __syncthreads();

    compute_chunk<80>(xs[0], wds4, base, th, vr, vc, ut, sprev, bw);
    __syncthreads();   // all reads of xs done before aliasing flush staging

    // ---- flush: stage ALL couts' bit-words into LDS (aliased over xs), then
    //      full-line coalesced float4 stores; single barrier ----
    float* outb = out + (size_t)b * (CO * HH * WW * TT);
    unsigned* stg = (unsigned*)&xs[0][0];   // 8 * 256*5 words = 40 KB, stride 5
#pragma unroll
    for (int j = 0; j < CO; ++j) {
#pragma unroll
        for (int w = 0; w < 4; ++w)
            stg[j * 1280 + tid * 5 + w] = bw[j * 4 + w];
    }
    __syncthreads();
#pragma unroll
    for (int j = 0; j < CO; ++j) {
#pragma unroll
        for (int k = 0; k < 25; ++k) {
            const int idx = tid + k * 256;        // 0..6399
            const int u   = idx / 25;             // site 0..255
            const int tt  = (idx - u * 25) * 4;   // t0 of this float4
            const unsigned bs = stg[j * 1280 + u * 5 + (tt >> 5)] >> (tt & 31);
            float4 v;
            v.x = (float)( bs        & 1u);
            v.y = (float)((bs >> 1)  & 1u);
            v.z = (float)((bs >> 2)  & 1u);
            v.w = (float)((bs >> 3)  & 1u);
            const int rr = u >> 4, cc = u & 15;
            *(float4*)(outb + (((size_t)j * HH + (h0 + rr)) * WW + (w0 + cc)) * TT + tt) = v;
        }
    }
}

extern "C" void kernel_launch(void* const* d_in, const int* in_sizes, int n_in,
                              void* d_out, int out_size, void* d_ws, size_t ws_size,
                              hipStream_t stream) {
    const float* x      = (const float*)d_in[0];
    const float* wgt    = (const float*)d_in[1];
    const float* thresh = (const float*)d_in[2];
    float* out = (float*)d_out;
    (void)d_ws; (void)ws_size;   // no workspace: avoids any ws-size assumption

    sconv2d_spike_kernel<<<dim3(32 * 16), dim3(256), 0, stream>>>(x, wgt, thresh, out);
}

// Round 3
// 980.333 us; speedup vs baseline: 1.1197x; 1.1197x over previous
//
#include <hip/hip_runtime.h>

#define HH 64
#define WW 64
#define TT 100
#define CO 8
#define KS 6
#define LP 2
#define TS 8          // spatial tile side
#define HS 13         // halo side = TS + KS - 1
#define NS 169        // HS*HS halo sites
#define NF4 25        // float4 per site time-row (100 t)
#define NTHR 128

__device__ __forceinline__ float stepu(float u, float s, float th, float wx) {
    // u = (u - s*th) + wx  -- exact reference association, no contraction
    return __fadd_rn(__fsub_rn(u, __fmul_rn(s, th)), wx);
}

#define FMA4(ACC, WD) \
    ACC.x = __fmaf_rn((WD), xv.x, ACC.x); \
    ACC.y = __fmaf_rn((WD), xv.y, ACC.y); \
    ACC.z = __fmaf_rn((WD), xv.z, ACC.z); \
    ACC.w = __fmaf_rn((WD), xv.w, ACC.w);

#define SCAN4(J) { \
    float u = ut[J], s = sprev[J]; unsigned m = 0u; \
    u = stepu(u, s, th, wx[J].x); s = (u > 0.f) ? 1.f : 0.f; m |= (u > 0.f) ? 1u : 0u; \
    u = stepu(u, s, th, wx[J].y); s = (u > 0.f) ? 1.f : 0.f; m |= (u > 0.f) ? 2u : 0u; \
    u = stepu(u, s, th, wx[J].z); s = (u > 0.f) ? 1.f : 0.f; m |= (u > 0.f) ? 4u : 0u; \
    u = stepu(u, s, th, wx[J].w); s = (u > 0.f) ? 1.f : 0.f; m |= (u > 0.f) ? 8u : 0u; \
    ut[J] = u; sprev[J] = s; cb[J] |= m << sh; }

__global__ __launch_bounds__(128, 1)
void sconv2d_spike_kernel(const float* __restrict__ x,
                          const float* __restrict__ wgt,
                          const float* __restrict__ thresh,
                          float* __restrict__ out)
{
    __shared__ float4   xh[NS * NF4];          // 67.6 KB: full-time halo
    __shared__ float4   wds4[KS * KS][2];      // 1.2 KB: [tap][co-quartet]
    __shared__ unsigned stg[CO * 64 * 5];      // 10 KB: spike bit-words

    const int tid = threadIdx.x;
    for (int i = tid; i < KS * KS * CO; i += NTHR) {
        const int co  = i / (KS * KS);
        const int tap = i - co * (KS * KS);
        ((float*)wds4)[tap * 8 + co] = wgt[i];
    }
    const float th = thresh[0];

    // grid = 32 images x 64 tiles (8x8 grid of 8x8 tiles)
    const int blk = blockIdx.x;
    const int b   = blk >> 6;
    const int tb  = blk & 63;
    const int h0  = (tb >> 3) * TS;
    const int w0  = (tb & 7) * TS;
    const int coq  = tid >> 6;        // 0..1 -> couts coq*4..coq*4+3
    const int site = tid & 63;
    const int rr   = site >> 3;
    const int cc   = site & 7;

    const float* xb = x + (size_t)b * (HH * WW * TT);

    // ---- stage: full time series of the 13x13 halo, zero-padded in LDS ----
    // consecutive slots = consecutive global addresses (contiguous per wave)
    for (int k = 0; k < 34; ++k) {
        const int i = tid + k * NTHR;
        if (i < NS * NF4) {
            const int s  = i / NF4;
            const int tg = i - s * NF4;
            const int hr = s / HS, hc = s - hr * HS;
            const int hh = h0 - LP + hr, ww = w0 - LP + hc;
            float4 v = make_float4(0.f, 0.f, 0.f, 0.f);
            if ((unsigned)hh < (unsigned)HH && (unsigned)ww < (unsigned)WW)
                v = *(const float4*)(xb + ((size_t)(hh * WW + ww)) * TT + tg * 4);
            xh[i] = v;
        }
    }
    __syncthreads();

    // ---- compute: conv (kh-major FMA chain, bit-exact) + scan, all 100 t ----
    float ut[4], sprev[4];
#pragma unroll
    for (int j = 0; j < 4; ++j) { ut[j] = 0.f; sprev[j] = 0.f; }

    const int vbase = (rr * HS + cc) * NF4;

#pragma unroll 1                       // keep per-chunk code resident in I$
    for (int g = 0; g < 5; ++g) {      // 5 chunks x 20 timesteps
        unsigned cb[4] = {0u, 0u, 0u, 0u};
#pragma unroll
        for (int tgl = 0; tgl < 5; ++tgl) {
            float4 wx[4];
#pragma unroll
            for (int j = 0; j < 4; ++j) wx[j] = make_float4(0.f, 0.f, 0.f, 0.f);
#pragma unroll
            for (int kh = 0; kh < KS; ++kh) {
#pragma unroll
                for (int kw = 0; kw < KS; ++kw) {
                    const float4 xv = xh[vbase + (kh * HS + kw) * NF4 + g * 5 + tgl];
                    const float4 wv = wds4[kh * KS + kw][coq];   // wave-uniform broadcast
                    FMA4(wx[0], wv.x); FMA4(wx[1], wv.y);
                    FMA4(wx[2], wv.z); FMA4(wx[3], wv.w);
                }
            }
            const int sh = tgl * 4;
            SCAN4(0); SCAN4(1); SCAN4(2); SCAN4(3);
        }
        // 20 bits per co for this chunk -> LDS (runtime g is an LDS index, not
        // a register-array index: no scratch)
#pragma unroll
        for (int j = 0; j < 4; ++j)
            stg[((coq * 4 + j) * 64 + site) * 5 + g] = cb[j];
    }
    __syncthreads();

    // ---- flush: bit expansion, contiguous float4 stores (1024B per wave) ----
    float* outb = out + (size_t)b * (CO * HH * WW * TT);
#pragma unroll 4
    for (int k = 0; k < 100; ++k) {
        const int idx = tid + k * NTHR;       // 0..12799
        const int co  = idx / 1600;
        const int rem = idx - co * 1600;
        const int u   = rem / 25;             // site 0..63
        const int tt  = (rem - u * 25) * 4;   // t0 of this float4 (0..96)
        const int g   = tt / 20;              // chunk word
        const int sh  = tt - g * 20;          // bit offset within word (<=16)
        const unsigned bs = stg[(co * 64 + u) * 5 + g] >> sh;
        float4 v;
        v.x = (float)( bs        & 1u);
        v.y = (float)((bs >> 1)  & 1u);
        v.z = (float)((bs >> 2)  & 1u);
        v.w = (float)((bs >> 3)  & 1u);
        const int r2 = u >> 3, c2 = u & 7;
        *(float4*)(outb + (((size_t)co * HH + (h0 + r2)) * WW + (w0 + c2)) * TT + tt) = v;
    }
}

extern "C" void kernel_launch(void* const* d_in, const int* in_sizes, int n_in,
                              void* d_out, int out_size, void* d_ws, size_t ws_size,
                              hipStream_t stream) {
    const float* x      = (const float*)d_in[0];
    const float* wgt    = (const float*)d_in[1];
    const float* thresh = (const float*)d_in[2];
    float* out = (float*)d_out;
    (void)d_ws; (void)ws_size;

    sconv2d_spike_kernel<<<dim3(32 * 64), dim3(NTHR), 0, stream>>>(x, wgt, thresh, out);
}